// Round 7
// baseline (258.466 us; speedup 1.0000x reference)
//
#include <hip/hip_runtime.h>

typedef unsigned short u16;
typedef __attribute__((ext_vector_type(8))) short bf16x8;
typedef __attribute__((ext_vector_type(4))) float f32x4;

__device__ __forceinline__ float bf2f(u16 u) {
  union { unsigned u; float f; } c; c.u = ((unsigned)u) << 16; return c.f;
}
__device__ __forceinline__ u16 f2bf(float f) {
  union { float f; unsigned u; } c; c.f = f;
  unsigned u = c.u;
  return (u16)((u + 0x7FFFu + ((u >> 16) & 1u)) >> 16);
}
// async global->LDS, 16B per lane; LDS dest = wave-uniform base + lane*16
__device__ __forceinline__ void gld16(const void* g, void* l) {
  __builtin_amdgcn_global_load_lds(
      (__attribute__((address_space(1))) void*)g,
      (__attribute__((address_space(3))) void*)l, 16, 0, 0);
}

#define BB 32      // batch
#define CC 256     // channels
#define NN 1024    // H*W

// ---------------- 0. convert weights/biases fp32 -> bf16 --------------------
__global__ __launch_bounds__(256) void convert_w_kernel(
    const float* __restrict__ Wk, const float* __restrict__ bk,
    const float* __restrict__ Wp, const float* __restrict__ bp,
    u16* __restrict__ Wkb, u16* __restrict__ bkb,
    u16* __restrict__ Wpb, u16* __restrict__ bpb)
{
  int b = blockIdx.x, t = threadIdx.x;
  const float* src; u16* dst; int idx, n;
  if (b < 768)       { src = Wk; dst = Wkb; idx = b * 256 + t;        n = 196608; }
  else if (b < 771)  { src = bk; dst = bkb; idx = (b - 768) * 256 + t; n = 768;   }
  else if (b < 1027) { src = Wp; dst = Wpb; idx = (b - 771) * 256 + t; n = 65536; }
  else               { src = bp; dst = bpb; idx = t;                  n = 256;    }
  if (idx < n) dst[idx] = f2bf(src[idx]);
}

// ---------------- 1. BatchNorm stats: per-channel mean/var -> scale/shift ----
__global__ __launch_bounds__(256) void bn_stats_kernel(
    const float* __restrict__ x, const float* __restrict__ gamma,
    const float* __restrict__ beta, float* __restrict__ scl, float* __restrict__ sft)
{
  int c = blockIdx.x;
  int tid = threadIdx.x;
  float s = 0.f, q = 0.f;
  for (int g = tid; g < 8192; g += 256) {
    int b = g >> 8;
    int n = (g & 255) * 4;
    float4 v = *reinterpret_cast<const float4*>(x + (((size_t)(b * CC + c)) << 10) + n);
    s += v.x + v.y + v.z + v.w;
    q += v.x * v.x + v.y * v.y + v.z * v.z + v.w * v.w;
  }
  __shared__ float rs[256], rq[256];
  rs[tid] = s; rq[tid] = q;
  __syncthreads();
  for (int off = 128; off > 0; off >>= 1) {
    if (tid < off) { rs[tid] += rs[tid + off]; rq[tid] += rq[tid + off]; }
    __syncthreads();
  }
  if (tid == 0) {
    float mean = rs[0] * (1.f / 32768.f);
    float var  = rq[0] * (1.f / 32768.f) - mean * mean;
    float rstd = rsqrtf(var + 1e-5f);
    float g = gamma[c] * rstd;
    scl[c] = g;
    sft[c] = beta[c] - mean * g;
  }
}

// ---------------- 2. normalize + transpose [B,C,N] -> t[B,N,C] (bf16) -------
__global__ __launch_bounds__(256) void norm_transpose_kernel(
    const float* __restrict__ x, const float* __restrict__ scl,
    const float* __restrict__ sft, u16* __restrict__ t)
{
  __shared__ float tile[64][65];
  int b = blockIdx.z, n0 = blockIdx.x * 64, c0 = blockIdx.y * 64;
  int tid = threadIdx.x;
  int hi = tid >> 4, lo4 = (tid & 15) * 4;
  #pragma unroll
  for (int r = 0; r < 4; ++r) {
    int cl = r * 16 + hi;
    int c = c0 + cl;
    float4 v = *reinterpret_cast<const float4*>(
        x + (((size_t)(b * CC + c)) << 10) + n0 + lo4);
    float sc = scl[c], sh = sft[c];
    tile[cl][lo4 + 0] = v.x * sc + sh;
    tile[cl][lo4 + 1] = v.y * sc + sh;
    tile[cl][lo4 + 2] = v.z * sc + sh;
    tile[cl][lo4 + 3] = v.w * sc + sh;
  }
  __syncthreads();
  #pragma unroll
  for (int r = 0; r < 4; ++r) {
    int nl = r * 16 + hi;
    ushort4 o;
    o.x = f2bf(tile[lo4 + 0][nl]);
    o.y = f2bf(tile[lo4 + 1][nl]);
    o.z = f2bf(tile[lo4 + 2][nl]);
    o.w = f2bf(tile[lo4 + 3][nl]);
    *reinterpret_cast<ushort4*>(t + ((size_t)(b * NN + n0 + nl)) * CC + c0 + lo4) = o;
  }
}

// ---------------- 3. NT bf16 GEMM, m97 staging + vectorized epilogue --------
// C[m,n] = f(scale * sum_k A[m,k]*B[n,k] + bias[n])
// mode 0: bf16 store (vectorized via LDS transpose)
// mode 1: transposed store vt[rr>>10][col][rr&1023] (bf16, ushort4)
// mode 2: proj + residual: outf[(b*256+col)<<10 | n] = v + xres[...] (fp32)
// mode 3: S-exp: store exp(scale*acc) bf16 + fused row sums (vectorized)
// mode 4: PV: store acc * (1/rowsum[row]) bf16 (vectorized)
__global__ __launch_bounds__(256) void gemm_nt_kernel(
    const u16* __restrict__ A, int lda, size_t sA,
    const u16* __restrict__ B, int ldb, size_t sB,
    u16* __restrict__ C, int ldc, size_t sC,
    int K, const u16* __restrict__ bias, float scale, int mode,
    const float* __restrict__ xres, float* __restrict__ outf,
    float* __restrict__ rowsum)
{
  // 34.8 KB: staging As/Bs (16 KB, live in K-loop) union P-tile (epilogue)
  __shared__ u16 smem[17408];
  u16* As = smem;            // 128*32, unpadded (global_load_lds lane-contig)
  u16* Bs = smem + 4096;     // 128*32
  int tid = threadIdx.x;
  int m0 = blockIdx.x * 128, n0 = blockIdx.y * 128;
  const u16* Ab = A + (size_t)blockIdx.z * sA;
  const u16* Bb = B + (size_t)blockIdx.z * sB;
  u16* Cb = C + (size_t)blockIdx.z * sC;

  int lane = tid & 63, w = tid >> 6;
  int lq = lane & 15, quad = lane >> 4;
  int wm = (w >> 1) * 64, wn = (w & 1) * 64;
  int ar = lane >> 2, ac = (lane & 3) * 8;   // staging: 4 lanes/row, 16B each
  int rb = w * 32;                            // wave's 32-row staging slice

  f32x4 zero = {0.f, 0.f, 0.f, 0.f};
  f32x4 acc[4][4];
  #pragma unroll
  for (int i = 0; i < 4; ++i)
    #pragma unroll
    for (int j = 0; j < 4; ++j) acc[i][j] = zero;

  for (int k0 = 0; k0 < K; k0 += 32) {
    __syncthreads();   // previous tile's ds_reads complete before overwrite
    gld16(Ab + (size_t)(m0 + rb +      ar) * lda + k0 + ac, &As[(rb     ) * 32]);
    gld16(Ab + (size_t)(m0 + rb + 16 + ar) * lda + k0 + ac, &As[(rb + 16) * 32]);
    gld16(Bb + (size_t)(n0 + rb +      ar) * ldb + k0 + ac, &Bs[(rb     ) * 32]);
    gld16(Bb + (size_t)(n0 + rb + 16 + ar) * ldb + k0 + ac, &Bs[(rb + 16) * 32]);
    __syncthreads();   // compiler drains vmcnt before barrier
    bf16x8 af[4], bfr[4];
    #pragma unroll
    for (int i = 0; i < 4; ++i) {
      af[i]  = *reinterpret_cast<const bf16x8*>(&As[(wm + i * 16 + lq) * 32 + quad * 8]);
      bfr[i] = *reinterpret_cast<const bf16x8*>(&Bs[(wn + i * 16 + lq) * 32 + quad * 8]);
    }
    #pragma unroll
    for (int i = 0; i < 4; ++i)
      #pragma unroll
      for (int j = 0; j < 4; ++j)
        acc[i][j] = __builtin_amdgcn_mfma_f32_16x16x32_bf16(af[i], bfr[j], acc[i][j], 0, 0, 0);
  }

  if (mode == 1) {
    #pragma unroll
    for (int j = 0; j < 4; ++j) {
      int col = n0 + wn + j * 16 + lq;
      float bv = bias ? bf2f(bias[col]) : 0.f;
      #pragma unroll
      for (int i = 0; i < 4; ++i) {
        int rbase = m0 + wm + i * 16 + quad * 4;
        int b = rbase >> 10, n = rbase & 1023;
        ushort4 o;
        o.x = f2bf(acc[i][j][0] * scale + bv);
        o.y = f2bf(acc[i][j][1] * scale + bv);
        o.z = f2bf(acc[i][j][2] * scale + bv);
        o.w = f2bf(acc[i][j][3] * scale + bv);
        *reinterpret_cast<ushort4*>(&Cb[(size_t)b * 262144 + (size_t)col * 1024 + n]) = o;
      }
    }
  } else if (mode == 2) {
    #pragma unroll
    for (int j = 0; j < 4; ++j) {
      int col = n0 + wn + j * 16 + lq;
      float bv = bias ? bf2f(bias[col]) : 0.f;
      #pragma unroll
      for (int i = 0; i < 4; ++i) {
        int rbase = m0 + wm + i * 16 + quad * 4;
        int b = rbase >> 10, n = rbase & 1023;
        size_t idx = (((size_t)(b * CC + col)) << 10) + n;
        float4 xv = *reinterpret_cast<const float4*>(xres + idx);
        float4 o;
        o.x = acc[i][j][0] * scale + bv + xv.x;
        o.y = acc[i][j][1] * scale + bv + xv.y;
        o.z = acc[i][j][2] * scale + bv + xv.z;
        o.w = acc[i][j][3] * scale + bv + xv.w;
        *reinterpret_cast<float4*>(outf + idx) = o;
      }
    }
  } else {
    // modes 0/3/4: vectorized epilogue via LDS P-tile (128 rows x 136 stride)
    __syncthreads();   // all waves done reading As/Bs (aliased with P-tile)
    #pragma unroll
    for (int j = 0; j < 4; ++j) {
      int col = wn + j * 16 + lq;
      float bv = bias ? bf2f(bias[n0 + col]) : 0.f;
      #pragma unroll
      for (int i = 0; i < 4; ++i) {
        int rloc = wm + i * 16 + quad * 4;
        #pragma unroll
        for (int r = 0; r < 4; ++r) {
          float v = acc[i][j][r] * scale + bv;
          if (mode == 3) v = __expf(v);
          smem[(rloc + r) * 136 + col] = f2bf(v);
        }
      }
    }
    __syncthreads();
    int g16 = tid & 15, row16 = tid >> 4;   // 16 threads per row, 16 rows/pass
    #pragma unroll
    for (int p = 0; p < 8; ++p) {
      int lr = p * 16 + row16;
      bf16x8 vv = *reinterpret_cast<const bf16x8*>(&smem[lr * 136 + g16 * 8]);
      if (mode == 3) {
        float part = 0.f;
        #pragma unroll
        for (int j = 0; j < 8; ++j) part += bf2f((u16)vv[j]);
        part += __shfl_xor(part, 1, 64);
        part += __shfl_xor(part, 2, 64);
        part += __shfl_xor(part, 4, 64);
        part += __shfl_xor(part, 8, 64);
        if (g16 == 0) atomicAdd(&rowsum[blockIdx.z * 1024 + m0 + lr], part);
      } else if (mode == 4) {
        float linv = 1.f / rowsum[blockIdx.z * 1024 + m0 + lr];
        #pragma unroll
        for (int j = 0; j < 8; ++j) vv[j] = (short)f2bf(bf2f((u16)vv[j]) * linv);
      }
      *reinterpret_cast<bf16x8*>(&Cb[(size_t)(m0 + lr) * ldc + n0 + g16 * 8]) = vv;
    }
  }
}

extern "C" void kernel_launch(void* const* d_in, const int* in_sizes, int n_in,
                              void* d_out, int out_size, void* d_ws, size_t ws_size,
                              hipStream_t stream) {
  const float* x     = (const float*)d_in[0];
  const float* gamma = (const float*)d_in[1];
  const float* beta  = (const float*)d_in[2];
  const float* Wkqv  = (const float*)d_in[3];
  const float* bkqv  = (const float*)d_in[4];
  const float* Wproj = (const float*)d_in[5];
  const float* bproj = (const float*)d_in[6];
  float* out = (float*)d_out;          // fp32 [32,256,32,32]

  // ---- workspace layout ----
  char* ws = (char*)d_ws;
  float* scl    = (float*)ws;                   // 256 f32
  float* sft    = (float*)(ws + 1024);          // 256 f32
  u16* Wkb = (u16*)(ws + 4096);                 // 196608 bf16
  u16* bkb = Wkb + 196608;
  u16* Wpb = bkb + 768;
  u16* bpb = Wpb + 65536;
  float* rowsum = (float*)(ws + 532480);        // 32*1024 f32 = 128 KB
  u16* qk   = (u16*)(ws + 1048576);             // [32768,512] bf16 = 32 MB
  u16* vt   = qk + (size_t)32768 * 512;         // [32,256,1024] bf16 = 16 MB
  u16* o_pv = vt + (size_t)32 * 256 * 1024;     // [32768,256] bf16 = 16 MB
  u16* Sc   = o_pv + (size_t)32768 * 256;       // S region (rest of ws)
  size_t s_base = 1048576 + (33554432 + 16777216 + 16777216);
  long avail = (long)ws_size - (long)s_base;
  int bpc = (int)(avail / 2097152);             // batches per S chunk (2 MB each)
  if (bpc < 1) bpc = 1;
  if (bpc > 32) bpc = 32;
  u16* t = (u16*)d_out;   // bf16 scratch in d_out, dead before mode-2 writes

  // 0. weight conversion + rowsum zero
  convert_w_kernel<<<dim3(1028), dim3(256), 0, stream>>>(
      Wkqv, bkqv, Wproj, bproj, Wkb, bkb, Wpb, bpb);
  hipMemsetAsync(rowsum, 0, 32 * 1024 * sizeof(float), stream);
  // 1. BN stats
  bn_stats_kernel<<<dim3(256), dim3(256), 0, stream>>>(x, gamma, beta, scl, sft);
  // 2. normalize + transpose -> t [B,N,C]
  norm_transpose_kernel<<<dim3(16, 4, 32), dim3(256), 0, stream>>>(x, scl, sft, t);
  // 3a. qk = t @ Wkqv[0:512]^T + b[0:512]
  gemm_nt_kernel<<<dim3(256, 4, 1), dim3(256), 0, stream>>>(
      t, 256, 0, Wkb, 256, 0, qk, 512, 0, 256, bkb, 1.0f, 0, nullptr, nullptr, nullptr);
  // 3b. vt[b,c,n] = (t @ Wkqv[512:768]^T + b[512:768])^T
  gemm_nt_kernel<<<dim3(256, 2, 1), dim3(256), 0, stream>>>(
      t, 256, 0, Wkb + 512 * 256, 256, 0, vt, 0, 0, 256, bkb + 512, 1.0f, 1,
      nullptr, nullptr, nullptr);
  // 4-7. attention: P=exp(QK^T/16) with fused row sums, then O = P V / l
  for (int b0 = 0; b0 < 32; b0 += bpc) {
    int nb = (32 - b0 < bpc) ? (32 - b0) : bpc;
    const u16* qc = qk + (size_t)b0 * 1024 * 512;
    gemm_nt_kernel<<<dim3(8, 8, nb), dim3(256), 0, stream>>>(
        qc, 512, (size_t)1024 * 512, qc + 256, 512, (size_t)1024 * 512,
        Sc, 1024, (size_t)1024 * 1024, 256, nullptr, 0.0625f, 3,
        nullptr, nullptr, rowsum + (size_t)b0 * 1024);
    gemm_nt_kernel<<<dim3(8, 2, nb), dim3(256), 0, stream>>>(
        Sc, 1024, (size_t)1024 * 1024, vt + (size_t)b0 * 262144, 1024, (size_t)262144,
        o_pv + (size_t)b0 * 262144, 256, (size_t)262144, 1024, nullptr, 1.0f, 4,
        nullptr, nullptr, rowsum + (size_t)b0 * 1024);
  }
  // 8+9 fused: out[b,c,n] = (o_pv @ Wproj^T + bproj)[n,c] + x[b,c,n]  (fp32)
  gemm_nt_kernel<<<dim3(256, 2, 1), dim3(256), 0, stream>>>(
      o_pv, 256, 0, Wpb, 256, 0, nullptr, 0, 0, 256, bpb, 1.0f, 2, x, out, nullptr);
}